// Round 11
// baseline (42.357 us; speedup 1.0000x reference)
//
#include <hip/hip_runtime.h>
#include <stdint.h>

// 7x7 stride-2 VALID cross-correlation, X: 4096x4096 fp32, out: 2045x2045 fp32.
// out[i,j] = sum_{p,q} X[2i+p, 2j+q] * W[p,q]
//
// Tile: 32 output rows x 64 cols; grid 512 blocks x 4 horizontally-chained
// tiles. global_load_lds DMA staging with NT cache policy (aux=2: no L3
// allocation on the read fill -- X is single-use), double-buffered LDS
// (2 x 40 KiB -> 2 blocks/CU), counted s_waitcnt vmcnt(10) + raw s_barrier
// (next tile's DMA stays in flight across barriers). Nontemporal output
// stores (out is never re-read; keep it out of the L3 fill path).
// LDS bank-quad swizzle s in {0,1,4,5} on chunks<32.

static constexpr int H     = 4096;
static constexpr int OUT   = 2045;           // (4096-7)/2 + 1
static constexpr int P4    = 36;             // float4 slots per LDS row
static constexpr int ROWS  = 69;             // tile input-row footprint
static constexpr int SLOTS = ROWS * P4;      // 2484 real slots
static constexpr int NIT   = 10;             // 2560 staged (76 dummies, never read)
static constexpr int ALLOC = NIT * 256;      // 2560 slots = 40 KiB per buffer
static constexpr int NT    = 4;              // tiles chained per block
static constexpr int AUXNT = 2;              // cpol NT bit (gfx940+: bit1 = NT)

__device__ __forceinline__ int sel(int q) {  // {0,1,2,3} -> {0,1,4,5}
    return (q & 1) | ((q & 2) << 1);
}
__device__ __forceinline__ int swz(int u, int s) {
    return (u < 32) ? (u ^ s) : u;           // chunks 32..35 (halo) unswizzled
}

__global__ __launch_bounds__(256) void conv7s2_kernel(
    const float* __restrict__ X,
    const float* __restrict__ W,
    float* __restrict__ out)
{
    __shared__ float4 lds4[2][ALLOC];        // 81920 B -> 2 blocks/CU

    const int t = threadIdx.x;
    const int b = blockIdx.x;

    // Uniform-address weight loads -> SGPRs.
    float w[49];
#pragma unroll
    for (int i = 0; i < 49; ++i) w[i] = W[i];

    // Staging decomposition (tile-independent): slot l = t + 256*it ->
    // (lrow, u); slot u of row lrow holds global chunk swz(u, sel((lrow>>2)&3)).
    int lrowA[NIT], G4A[NIT];
#pragma unroll
    for (int it = 0; it < NIT; ++it) {
        const int l  = t + 256 * it;
        const int lr = l / P4;
        const int u  = l - lr * P4;
        lrowA[it] = lr;                      // up to 71 for dummy slots
        G4A[it]   = 4 * swz(u, sel((lr >> 2) & 3));
    }

    // ty-minor lane mapping.
    const int tysub = t & 3;
    const int c     = (t >> 2) & 15;   // col-group: output cols 4c..4c+3
    const int wv    = t >> 6;
    const int rg    = tysub + 4 * wv;  // row-group: output rows 2rg, 2rg+1
    const int c2    = 2 * c;

    auto stage = [&](int buf, int tid) {
        const int C0 = (tid & 31) * 128;
        const int R0 = (tid >> 5) * 64;
#pragma unroll
        for (int it = 0; it < NIT; ++it) {
            const int l = t + 256 * it;      // all lanes active: 10 DMA/wave
            int grow = R0 + lrowA[it];  if (grow > H - 1) grow = H - 1;  // garbage/dummy
            int gcol = C0 + G4A[it];    if (gcol > H - 4) gcol = H - 4;  // guarded outputs
            const float* gp = X + (size_t)grow * H + gcol;
            __builtin_amdgcn_global_load_lds(
                (const __attribute__((address_space(1))) uint32_t*)gp,
                (__attribute__((address_space(3))) uint32_t*)&lds4[buf][l],
                16, 0, AUXNT);               // NT: bypass L3 allocation
        }
    };

    // Prologue: tile 0 -> buffer 0 (10 outstanding/wave).
    stage(0, NT * b);

#pragma unroll
    for (int k = 0; k < NT; ++k) {
        const int tid = NT * b + k;
        const int bx  = tid & 31;
        const int by  = tid >> 5;
        const int cur = k & 1;

        // Issue next tile's DMA first; it streams during this tile's compute.
        if (k + 1 < NT) stage(cur ^ 1, tid + 1);

        // Wait ONLY for tile k's loads (leave the 10 newer ones in flight).
        if (k + 1 < NT) { asm volatile("s_waitcnt vmcnt(10)" ::: "memory"); }
        else           { asm volatile("s_waitcnt vmcnt(0)"  ::: "memory"); }
        __builtin_amdgcn_sched_barrier(0);
        __builtin_amdgcn_s_barrier();          // all waves' tile-k DMA landed
        __builtin_amdgcn_sched_barrier(0);

        float acc0[4] = {0.f, 0.f, 0.f, 0.f};
        float acc1[4] = {0.f, 0.f, 0.f, 0.f};

#pragma unroll
        for (int r = 0; r < 9; ++r) {
            const int lrow = 4 * rg + r;
            const int base = lrow * P4;
            const int s    = sel((rg + (r >> 2)) & 3);

            float rv[16];                      // static register indices only
#pragma unroll
            for (int i = 0; i < 4; ++i) {
                const float4 v = lds4[cur][base + swz(c2 + i, s)];
                rv[4 * i + 0] = v.x;
                rv[4 * i + 1] = v.y;
                rv[4 * i + 2] = v.z;
                rv[4 * i + 3] = v.w;
            }

#pragma unroll
            for (int q = 0; q < 7; ++q) {
#pragma unroll
                for (int j = 0; j < 4; ++j) {
                    const float cv = rv[2 * j + q];
                    if (r <= 6) acc0[j] = fmaf(cv, w[r * 7 + q],       acc0[j]);
                    if (r >= 2) acc1[j] = fmaf(cv, w[(r - 2) * 7 + q], acc1[j]);
                }
            }
        }

        const int x0 = bx * 64 + 4 * c;
        const int y0 = by * 32 + 2 * rg;
#pragma unroll
        for (int j = 0; j < 4; ++j) {
            const int x = x0 + j;
            if (x < OUT) {
                if (y0 < OUT)
                    __builtin_nontemporal_store(acc0[j], &out[(size_t)y0 * OUT + x]);
                if (y0 + 1 < OUT)
                    __builtin_nontemporal_store(acc1[j], &out[(size_t)(y0 + 1) * OUT + x]);
            }
        }

        // End-of-compute fence: next iteration's stage overwrites buf[cur].
        if (k + 1 < NT) {
            __builtin_amdgcn_sched_barrier(0);
            __builtin_amdgcn_s_barrier();
            __builtin_amdgcn_sched_barrier(0);
        }
    }
}

extern "C" void kernel_launch(void* const* d_in, const int* in_sizes, int n_in,
                              void* d_out, int out_size, void* d_ws, size_t ws_size,
                              hipStream_t stream) {
    const float* X = (const float*)d_in[0];
    const float* W = (const float*)d_in[1];
    float* out = (float*)d_out;

    conv7s2_kernel<<<dim3(512), 256, 0, stream>>>(X, W, out);   // 512 x 4 = 2048 tiles
}

// Round 13
// 26.868 us; speedup vs baseline: 1.5765x; 1.5765x over previous
//
#include <hip/hip_runtime.h>
#include <stdint.h>

// 7x7 stride-2 VALID cross-correlation, X: 4096x4096 fp32, out: 2045x2045 fp32.
// out[i,j] = sum_{p,q} X[2i+p, 2j+q] * W[p,q]
//
// Line-buffer ring: 4 column strips x 128 row-bands = 512 blocks (2/CU).
// Each block streams 37 input rows; each row staged as a DENSE ~4.1 KB
// contiguous run via 2 uniform global_load_lds per wave (waves 1-3's 2nd
// instr goes to a never-read scratch line -> exact per-wave vmcnt).
// Ring = 13 rows x 320 float4 (66.6 KB) + 1 KB scratch -> 2 blocks/CU.
// Per iteration: 2 output rows (h-split), 4 new input rows prefetched,
// counted s_waitcnt vmcnt(8), then LANDING BARRIER (cross-wave visibility
// -- the R12 bug), compute, top barrier before next overwrite.
// In-row involution swizzle u^((u>>3)&1) on BOTH the DMA source chunk and
// the LDS read -> 8 consecutive lanes cover all 8 bank quads (b128 floor).

static constexpr int H    = 4096;
static constexpr int OUT  = 2045;   // (4096-7)/2 + 1
static constexpr int PIT  = 320;    // float4 slots per ring row
static constexpr int RING = 13;     // 9-row window + 4 rows in flight
static constexpr int UMAX = 257;    // last useful chunk per row (258 chunks)

__device__ __forceinline__ int swz(int u) {   // involution, closed on [0,UMAX]
    return u ^ ((u >> 3) & 1);
}
__device__ __forceinline__ int mod13(int r) { // r <= 38
    if (r >= 26) r -= 26; else if (r >= 13) r -= 13;
    return r;
}

__device__ __forceinline__ void dma_row(const float* __restrict__ X,
                                        float4 (&ring)[RING][PIT],
                                        float4 (&scr)[64],
                                        int t, int sl, int grow, int FB)
{
    const float* rowp = X + (size_t)grow * H;
    {   // instr 0: slots 0..255 (all waves useful)
        const int u = t;
        int g = swz(u);                        // <= 255 here
        int col = FB + 4 * g; if (col > H - 4) col = H - 4;
        __builtin_amdgcn_global_load_lds(
            (const __attribute__((address_space(1))) uint32_t*)(rowp + col),
            (__attribute__((address_space(3))) uint32_t*)&ring[sl][u],
            16, 0, 0);
    }
    {   // instr 1: wave 0 -> slots 256..319; waves 1-3 -> scratch (dup loads)
        const int u = t + 256;
        const bool useful = (u < PIT);         // wave-uniform (t < 64)
        int g = swz(u); if (g > UMAX) g = UMAX;    // dup-clamp dummy chunks
        int col = FB + 4 * g; if (col > H - 4) col = H - 4;
        __attribute__((address_space(3))) uint32_t* dst = useful
            ? (__attribute__((address_space(3))) uint32_t*)&ring[sl][u]
            : (__attribute__((address_space(3))) uint32_t*)&scr[t & 63];
        __builtin_amdgcn_global_load_lds(
            (const __attribute__((address_space(1))) uint32_t*)(rowp + col),
            dst, 16, 0, 0);
    }
}

__global__ __launch_bounds__(256) void conv7s2_ring(
    const float* __restrict__ X,
    const float* __restrict__ W,
    float* __restrict__ out)
{
    __shared__ float4 ring[RING][PIT];         // 66,560 B
    __shared__ float4 scr[64];                 // 1,024 B (never read)

    const int t     = threadIdx.x;
    const int strip = blockIdx.x & 3;          // 4 strips x 512 out-cols
    const int band  = blockIdx.x >> 2;         // 128 bands x 16 out-rows
    const int X0    = strip * 512;
    const int FB    = strip * 1024;            // input col base (floats)
    const int R0    = band * 32;               // input row base

    // Uniform-address weight loads -> SGPRs.
    float w[49];
#pragma unroll
    for (int i = 0; i < 49; ++i) w[i] = W[i];

    const int c = t & 127;                     // col-group: out cols X0+4c..+3
    const int h = t >> 7;                      // row-half within the pair

    // Prologue: rows 0..8 (pair 0's window), 18 DMA/wave outstanding.
#pragma unroll
    for (int r = 0; r < 9; ++r) {
        int grow = R0 + r; if (grow > H - 1) grow = H - 1;   // feeds guarded rows
        dma_row(X, ring, scr, t, r, grow, FB);
    }

#pragma unroll 1
    for (int I = 0; I < 8; ++I) {
        // Top barrier: compute I-1 (all waves) done before slot overwrite.
        __builtin_amdgcn_sched_barrier(0);
        __builtin_amdgcn_s_barrier();
        __builtin_amdgcn_sched_barrier(0);

        if (I < 7) {
            // Issue pair I+1's 4 new rows (slots at offsets 9..12 mod 13:
            // disjoint from this pair's read slots 0..8).
#pragma unroll
            for (int rr = 0; rr < 4; ++rr) {
                const int r = 4 * I + 9 + rr;
                int grow = R0 + r; if (grow > H - 1) grow = H - 1;
                dma_row(X, ring, scr, t, mod13(r), grow, FB);
            }
            // Leave exactly the 8 just-issued DMA in flight; everything
            // older (rows <= 4I+8, prior stores) drains.
            asm volatile("s_waitcnt vmcnt(8)" ::: "memory");
        } else {
            asm volatile("s_waitcnt vmcnt(0)" ::: "memory");
        }
        __builtin_amdgcn_sched_barrier(0);
        __builtin_amdgcn_s_barrier();          // LANDING barrier: ALL waves'
        __builtin_amdgcn_sched_barrier(0);     // rows <= 4I+8 visible (R12 fix)

        float acc0 = 0.f, acc1 = 0.f, acc2 = 0.f, acc3 = 0.f;
        const int sbase = mod13(4 * I + 2 * h);
#pragma unroll
        for (int p = 0; p < 7; ++p) {
            int sp = sbase + p; if (sp >= RING) sp -= RING;
            const float4* rp = &ring[sp][0];
            float rv[16];                      // static register indices only
#pragma unroll
            for (int k = 0; k < 4; ++k) {
                const int u = 2 * c + k;
                const float4 v = rp[swz(u)];   // swizzle in address only
                rv[4*k+0] = v.x; rv[4*k+1] = v.y; rv[4*k+2] = v.z; rv[4*k+3] = v.w;
            }
#pragma unroll
            for (int q = 0; q < 7; ++q) {
                const float wv = w[p * 7 + q];
                acc0 = fmaf(rv[0 + q], wv, acc0);
                acc1 = fmaf(rv[2 + q], wv, acc1);
                acc2 = fmaf(rv[4 + q], wv, acc2);
                acc3 = fmaf(rv[6 + q], wv, acc3);
            }
        }

        const int y  = band * 16 + 2 * I + h;
        const int x0 = X0 + 4 * c;
        if (y < OUT) {
            float* op = out + (size_t)y * OUT + x0;
            if (x0 + 3 < OUT) {
                op[0] = acc0; op[1] = acc1; op[2] = acc2; op[3] = acc3;
            } else {
                if (x0     < OUT) op[0] = acc0;
                if (x0 + 1 < OUT) op[1] = acc1;
                if (x0 + 2 < OUT) op[2] = acc2;
                if (x0 + 3 < OUT) op[3] = acc3;
            }
        }
    }
}

extern "C" void kernel_launch(void* const* d_in, const int* in_sizes, int n_in,
                              void* d_out, int out_size, void* d_ws, size_t ws_size,
                              hipStream_t stream) {
    const float* X = (const float*)d_in[0];
    const float* W = (const float*)d_in[1];
    float* out = (float*)d_out;

    conv7s2_ring<<<dim3(512), 256, 0, stream>>>(X, W, out);  // 4 strips x 128 bands
}

// Round 14
// 24.242 us; speedup vs baseline: 1.7472x; 1.1083x over previous
//
#include <hip/hip_runtime.h>
#include <stdint.h>

// 7x7 stride-2 VALID cross-correlation, X: 4096x4096 fp32, out: 2045x2045 fp32.
// out[i,j] = sum_{p,q} X[2i+p, 2j+q] * W[p,q]
//
// BEST VARIANT (round 7, 23.7 us): tile 32 output rows x 64 cols; grid 512
// blocks x 4 horizontally-chained tiles. global_load_lds DMA staging (no data
// VGPRs -> nothing for the register allocator to spill), double-buffered LDS
// (2 x 40 KiB = 80 KiB -> 2 blocks/CU). Counted s_waitcnt vmcnt(10) + raw
// s_barrier per tile: the next tile's DMA stays in flight across the barrier.
// LDS bank-quad swizzle s in {0,1,4,5} on chunks<32 (applied to the per-lane
// GLOBAL source address; LDS dest stays lane-linear as global_load_lds
// requires). All register indices compile-time.
//
// Measured structural ceiling: reads are irreducible (64 MB X, FETCH=66 MB);
// no kernel on this box (incl. the harness's float4 copy, 3.145 TB/s
// read-half) exceeds ~3.1 TB/s read stream; 9 structural variants spanning
// issue depth / burst length / locality / cache policy / queue smoothness
// all land 23.7-29 us. Floor ~ 66MB/3.1TB/s = 21.3 us; this kernel: 23.7.

static constexpr int H     = 4096;
static constexpr int OUT   = 2045;           // (4096-7)/2 + 1
static constexpr int P4    = 36;             // float4 slots per LDS row
static constexpr int ROWS  = 69;             // tile input-row footprint
static constexpr int SLOTS = ROWS * P4;      // 2484 real slots
static constexpr int NIT   = 10;             // 2560 staged (76 dummies, never read)
static constexpr int ALLOC = NIT * 256;      // 2560 slots = 40 KiB per buffer
static constexpr int NT    = 4;              // tiles chained per block

__device__ __forceinline__ int sel(int q) {  // {0,1,2,3} -> {0,1,4,5}
    return (q & 1) | ((q & 2) << 1);
}
__device__ __forceinline__ int swz(int u, int s) {
    return (u < 32) ? (u ^ s) : u;           // chunks 32..35 (halo) unswizzled
}

__global__ __launch_bounds__(256) void conv7s2_kernel(
    const float* __restrict__ X,
    const float* __restrict__ W,
    float* __restrict__ out)
{
    __shared__ float4 lds4[2][ALLOC];        // 81920 B -> 2 blocks/CU

    const int t = threadIdx.x;
    const int b = blockIdx.x;

    // Uniform-address weight loads -> SGPRs.
    float w[49];
#pragma unroll
    for (int i = 0; i < 49; ++i) w[i] = W[i];

    // Staging decomposition (tile-independent): slot l = t + 256*it ->
    // (lrow, u); slot u of row lrow holds global chunk swz(u, sel((lrow>>2)&3)).
    int lrowA[NIT], G4A[NIT];
#pragma unroll
    for (int it = 0; it < NIT; ++it) {
        const int l  = t + 256 * it;
        const int lr = l / P4;
        const int u  = l - lr * P4;
        lrowA[it] = lr;                      // up to 71 for dummy slots
        G4A[it]   = 4 * swz(u, sel((lr >> 2) & 3));
    }

    // ty-minor lane mapping.
    const int tysub = t & 3;
    const int c     = (t >> 2) & 15;   // col-group: output cols 4c..4c+3
    const int wv    = t >> 6;
    const int rg    = tysub + 4 * wv;  // row-group: output rows 2rg, 2rg+1
    const int c2    = 2 * c;

    auto stage = [&](int buf, int tid) {
        const int C0 = (tid & 31) * 128;
        const int R0 = (tid >> 5) * 64;
#pragma unroll
        for (int it = 0; it < NIT; ++it) {
            const int l = t + 256 * it;      // all lanes active: 10 DMA/wave
            int grow = R0 + lrowA[it];  if (grow > H - 1) grow = H - 1;  // garbage/dummy
            int gcol = C0 + G4A[it];    if (gcol > H - 4) gcol = H - 4;  // guarded outputs
            const float* gp = X + (size_t)grow * H + gcol;
            __builtin_amdgcn_global_load_lds(
                (const __attribute__((address_space(1))) uint32_t*)gp,
                (__attribute__((address_space(3))) uint32_t*)&lds4[buf][l],
                16, 0, 0);
        }
    };

    // Prologue: tile 0 -> buffer 0 (10 outstanding/wave).
    stage(0, NT * b);

#pragma unroll
    for (int k = 0; k < NT; ++k) {
        const int tid = NT * b + k;
        const int bx  = tid & 31;
        const int by  = tid >> 5;
        const int cur = k & 1;

        // Issue next tile's DMA first; it streams during this tile's compute.
        if (k + 1 < NT) stage(cur ^ 1, tid + 1);

        // Wait ONLY for tile k's loads (leave the 10 newer ones in flight).
        if (k + 1 < NT) { asm volatile("s_waitcnt vmcnt(10)" ::: "memory"); }
        else           { asm volatile("s_waitcnt vmcnt(0)"  ::: "memory"); }
        __builtin_amdgcn_sched_barrier(0);
        __builtin_amdgcn_s_barrier();          // all waves' tile-k DMA landed
        __builtin_amdgcn_sched_barrier(0);

        float acc0[4] = {0.f, 0.f, 0.f, 0.f};
        float acc1[4] = {0.f, 0.f, 0.f, 0.f};

#pragma unroll
        for (int r = 0; r < 9; ++r) {
            const int lrow = 4 * rg + r;
            const int base = lrow * P4;
            const int s    = sel((rg + (r >> 2)) & 3);

            float rv[16];                      // static register indices only
#pragma unroll
            for (int i = 0; i < 4; ++i) {
                const float4 v = lds4[cur][base + swz(c2 + i, s)];
                rv[4 * i + 0] = v.x;
                rv[4 * i + 1] = v.y;
                rv[4 * i + 2] = v.z;
                rv[4 * i + 3] = v.w;
            }

#pragma unroll
            for (int q = 0; q < 7; ++q) {
#pragma unroll
                for (int j = 0; j < 4; ++j) {
                    const float cv = rv[2 * j + q];
                    if (r <= 6) acc0[j] = fmaf(cv, w[r * 7 + q],       acc0[j]);
                    if (r >= 2) acc1[j] = fmaf(cv, w[(r - 2) * 7 + q], acc1[j]);
                }
            }
        }

        const int x0 = bx * 64 + 4 * c;
        const int y0 = by * 32 + 2 * rg;
#pragma unroll
        for (int j = 0; j < 4; ++j) {
            const int x = x0 + j;
            if (x < OUT) {
                if (y0     < OUT) out[(size_t)y0       * OUT + x] = acc0[j];
                if (y0 + 1 < OUT) out[(size_t)(y0 + 1) * OUT + x] = acc1[j];
            }
        }

        // End-of-compute fence: next iteration's stage overwrites buf[cur].
        if (k + 1 < NT) {
            __builtin_amdgcn_sched_barrier(0);
            __builtin_amdgcn_s_barrier();
            __builtin_amdgcn_sched_barrier(0);
        }
    }
}

extern "C" void kernel_launch(void* const* d_in, const int* in_sizes, int n_in,
                              void* d_out, int out_size, void* d_ws, size_t ws_size,
                              hipStream_t stream) {
    const float* X = (const float*)d_in[0];
    const float* W = (const float*)d_in[1];
    float* out = (float*)d_out;

    conv7s2_kernel<<<dim3(512), 256, 0, stream>>>(X, W, out);   // 512 x 4 = 2048 tiles
}